// Round 1
// baseline (188.721 us; speedup 1.0000x reference)
//
#include <hip/hip_runtime.h>
#include <hip/hip_bf16.h>
#include <math.h>

#define BATCH   8192
#define NFIELD  24
#define FAC     16
#define PAIRS   276
#define HID     64
#define PG      4
#define PPG     (PAIRS / PG)   // 69 pairs per group
#define NBB     (BATCH / 64)   // 128 batch blocks of 64 rows

typedef __attribute__((ext_vector_type(8))) __bf16 bf16x8;
typedef __attribute__((ext_vector_type(4))) float f32x4;

// ---- workspace layout (bytes) ----
// xvT:    [128][24][2][64][8] bf16  = 6291456
// W1R:    [276][4][64][8]     bf16  = 1130496
// W2b:    [276][64]           bf16  =   35328
// partial:[PG][8192]          f32   =  131072
#define XVT_OFF  0
#define W1R_OFF  6291456
#define W2B_OFF  (W1R_OFF + 1130496)
#define PART_OFF (W2B_OFF + 35328)

// Gather v[inputs] -> bf16, layout [bb][field][half][row64][8]
__global__ void prep_embed(const int* __restrict__ inputs,
                           const float* __restrict__ v,
                           __hip_bfloat16* __restrict__ xvT) {
    int t = blockIdx.x * 256 + threadIdx.x;      // < 196608
    int field = t >> 13;
    int b = t & 8191;
    int idx = inputs[b * NFIELD + field];
    const float4* src = (const float4*)(v + (long)idx * FAC);
    union { __hip_bfloat16 h[16]; uint4 u[2]; } tmp;
    float4 a0 = src[0], a1 = src[1], a2 = src[2], a3 = src[3];
    tmp.h[0]  = __float2bfloat16(a0.x); tmp.h[1]  = __float2bfloat16(a0.y);
    tmp.h[2]  = __float2bfloat16(a0.z); tmp.h[3]  = __float2bfloat16(a0.w);
    tmp.h[4]  = __float2bfloat16(a1.x); tmp.h[5]  = __float2bfloat16(a1.y);
    tmp.h[6]  = __float2bfloat16(a1.z); tmp.h[7]  = __float2bfloat16(a1.w);
    tmp.h[8]  = __float2bfloat16(a2.x); tmp.h[9]  = __float2bfloat16(a2.y);
    tmp.h[10] = __float2bfloat16(a2.z); tmp.h[11] = __float2bfloat16(a2.w);
    tmp.h[12] = __float2bfloat16(a3.x); tmp.h[13] = __float2bfloat16(a3.y);
    tmp.h[14] = __float2bfloat16(a3.z); tmp.h[15] = __float2bfloat16(a3.w);
    int bb = b >> 6, row = b & 63;
    __hip_bfloat16* base = xvT + (long)bb * 24576 + field * 1024 + row * 8;
    *(uint4*)base         = tmp.u[0];
    *(uint4*)(base + 512) = tmp.u[1];
}

// Repack W1 into B-fragment order: W1R[p][t][lane][j] = W1[p][(lane>>4)*8+j][16t+(lane&15)]
__global__ void prep_w(const float* __restrict__ W1,
                       const float* __restrict__ W2,
                       __hip_bfloat16* __restrict__ W1R,
                       __hip_bfloat16* __restrict__ W2b) {
    int t = blockIdx.x * 256 + threadIdx.x;      // < 17664
    int p = t >> 6;
    int L = t & 63;
    int q = L >> 4, c = L & 15;
    union { __hip_bfloat16 h[8]; uint4 u; } buf;
#pragma unroll
    for (int tt = 0; tt < 4; ++tt) {
#pragma unroll
        for (int jj = 0; jj < 8; ++jj)
            buf.h[jj] = __float2bfloat16(W1[p * 2048 + (q * 8 + jj) * 64 + tt * 16 + c]);
        *(uint4*)(W1R + (p * 4 + tt) * 512 + L * 8) = buf.u;
    }
    W2b[p * 64 + L] = __float2bfloat16(W2[p * 64 + L]);
}

__global__ __launch_bounds__(256, 2) void ffm_main(
        const __hip_bfloat16* __restrict__ xvT,
        const __hip_bfloat16* __restrict__ W1R,
        const __hip_bfloat16* __restrict__ W2b,
        const float* __restrict__ b1,
        const float* __restrict__ b2,
        float* __restrict__ partial) {
    __shared__ __align__(16) __hip_bfloat16 xv_s[24576];  // 48 KB
    __shared__ __align__(16) __hip_bfloat16 w1_s[2048];   // 4 KB
    __shared__ __align__(16) __hip_bfloat16 w2_s[64];
    __shared__ __align__(16) float b1_s[64];
    __shared__ float b2_s;

    int tid  = threadIdx.x;
    int bb   = blockIdx.x & (NBB - 1);
    int pg   = blockIdx.x >> 7;
    int lane = tid & 63;
    int wave = tid >> 6;
    int col  = lane & 15;
    int quad = lane >> 4;

    // stage this block's 64-row embedding slab (48 KB, straight copy)
    {
        const uint4* src = (const uint4*)(xvT + (long)bb * 24576);
        uint4* dst = (uint4*)xv_s;
#pragma unroll
        for (int it = 0; it < 12; ++it) dst[tid + it * 256] = src[tid + it * 256];
    }

    // pair range and starting (i,j)
    int p0 = pg * PPG;
    int i = 0, rem = p0;
    while (rem >= NFIELD - 1 - i) { rem -= NFIELD - 1 - i; ++i; }
    int j = i + 1 + rem;

    float acc[4] = {0.f, 0.f, 0.f, 0.f};
    float b2acc = 0.f;

    // A-fragment base for rows (no field part): row_local = wave*16 + col, half = quad&1
    const int a_row_off = (quad & 1) * 512 + (wave * 16 + col) * 8;

    for (int p = p0; p < p0 + PPG; ++p) {
        __syncthreads();   // previous iteration's reads of w1_s done (also covers xv staging on iter 0)
        ((uint4*)w1_s)[tid] = ((const uint4*)(W1R + (long)p * 2048))[tid];
        if (tid < 8)  ((uint4*)w2_s)[tid] = ((const uint4*)(W2b + p * 64))[tid];
        if (tid >= 64 && tid < 80) ((uint4*)b1_s)[tid - 64] = ((const uint4*)(b1 + p * 64))[tid - 64];
        if (tid == 128) b2_s = b2[p];
        __syncthreads();

        int field = (quad < 2) ? i : j;
        bf16x8 af = *(const bf16x8*)(xv_s + field * 1024 + a_row_off);

        f32x4 c[4];
#pragma unroll
        for (int tt = 0; tt < 4; ++tt) {
            float bt = b1_s[tt * 16 + col];
            c[tt][0] = bt; c[tt][1] = bt; c[tt][2] = bt; c[tt][3] = bt;
        }
#pragma unroll
        for (int tt = 0; tt < 4; ++tt) {
            bf16x8 bf = *(const bf16x8*)(w1_s + (tt * 64 + lane) * 8);
            c[tt] = __builtin_amdgcn_mfma_f32_16x16x32_bf16(af, bf, c[tt], 0, 0, 0);
        }
#pragma unroll
        for (int tt = 0; tt < 4; ++tt) {
            float w2v = __bfloat162float(w2_s[tt * 16 + col]);
#pragma unroll
            for (int r = 0; r < 4; ++r) {
                float h = fmaxf(c[tt][r], 0.0f);
                acc[r] = fmaf(h, w2v, acc[r]);
            }
        }
        b2acc += b2_s;

        ++j;
        if (j == NFIELD) { ++i; j = i + 1; }
    }

    // add per-pair bias sum exactly once per row (only the col==0 slice)
    if (col == 0) {
        acc[0] += b2acc; acc[1] += b2acc; acc[2] += b2acc; acc[3] += b2acc;
    }
    // reduce over the 16 column-lanes within each quad group
#pragma unroll
    for (int m = 1; m < 16; m <<= 1) {
#pragma unroll
        for (int r = 0; r < 4; ++r) acc[r] += __shfl_xor(acc[r], m, 64);
    }
    if (col == 0) {
        f32x4 o; o[0] = acc[0]; o[1] = acc[1]; o[2] = acc[2]; o[3] = acc[3];
        *(f32x4*)&partial[pg * BATCH + bb * 64 + wave * 16 + quad * 4] = o;
    }
}

__global__ void finalize(const int* __restrict__ inputs,
                         const float* __restrict__ w,
                         const float* __restrict__ bsc,
                         const float* __restrict__ partial,
                         float* __restrict__ out) {
    int bidx = blockIdx.x * 256 + threadIdx.x;   // < 8192
    const int4* ip = (const int4*)(inputs + bidx * NFIELD);
    float l = 0.f;
#pragma unroll
    for (int q = 0; q < 6; ++q) {
        int4 v4 = ip[q];
        l += w[v4.x] + w[v4.y] + w[v4.z] + w[v4.w];
    }
    float s = l + bsc[0];
#pragma unroll
    for (int g = 0; g < PG; ++g) s += partial[g * BATCH + bidx];
    out[bidx] = 1.0f / (1.0f + expf(-s));
}

extern "C" void kernel_launch(void* const* d_in, const int* in_sizes, int n_in,
                              void* d_out, int out_size, void* d_ws, size_t ws_size,
                              hipStream_t stream) {
    const int*   inputs = (const int*)d_in[0];
    const float* w      = (const float*)d_in[1];
    const float* v      = (const float*)d_in[2];
    const float* bsc    = (const float*)d_in[3];
    const float* W1     = (const float*)d_in[4];
    const float* b1     = (const float*)d_in[5];
    const float* W2     = (const float*)d_in[6];
    const float* b2     = (const float*)d_in[7];
    float* out = (float*)d_out;

    char* ws = (char*)d_ws;
    __hip_bfloat16* xvT = (__hip_bfloat16*)(ws + XVT_OFF);
    __hip_bfloat16* W1R = (__hip_bfloat16*)(ws + W1R_OFF);
    __hip_bfloat16* W2b = (__hip_bfloat16*)(ws + W2B_OFF);
    float* partial      = (float*)(ws + PART_OFF);

    prep_embed<<<BATCH * NFIELD / 256, 256, 0, stream>>>(inputs, v, xvT);
    prep_w<<<PAIRS * 64 / 256, 256, 0, stream>>>(W1, W2, W1R, W2b);
    ffm_main<<<NBB * PG, 256, 0, stream>>>(xvT, W1R, W2b, b1, b2, partial);
    finalize<<<BATCH / 256, 256, 0, stream>>>(inputs, w, bsc, partial, out);
}

// Round 3
// 157.072 us; speedup vs baseline: 1.2015x; 1.2015x over previous
//
#include <hip/hip_runtime.h>
#include <hip/hip_bf16.h>
#include <math.h>

#define BATCH   8192
#define NFIELD  24
#define FAC     16
#define PAIRS   276
#define HID     64
#define PG      6
#define PPG     (PAIRS / PG)   // 46 pairs per group
#define NBB     (BATCH / 64)   // 128 batch blocks of 64 rows

typedef __attribute__((ext_vector_type(8))) __bf16 bf16x8;
typedef __attribute__((ext_vector_type(4))) float f32x4;

// ---- workspace layout (bytes) ----
// xvT:   [128][24][2][64][8] bf16             = 6,291,456
// combo: [276+1 pad][4608]                     = 1,276,416
//        per pair: [0,256) b1R col-major f32x4; [256,512) w2R; [512,4608) W1 frags
// partial:[PG][8192] f32                       =   196,608
// consts: [1] f32 (b[0] + sum b2)              =         4
#define XVT_OFF   0
#define COMBO_OFF 6291456
#define PART_OFF  (COMBO_OFF + 1276416)   // 7,567,872
#define CONST_OFF (PART_OFF + 196608)     // 7,764,480

// Gather v[inputs] -> bf16, layout [bb][field][half][row64][8] (flat, no pad)
__global__ void prep_embed(const int* __restrict__ inputs,
                           const float* __restrict__ v,
                           __hip_bfloat16* __restrict__ xvT) {
    int t = blockIdx.x * 256 + threadIdx.x;      // < 196608
    int field = t >> 13;
    int b = t & 8191;
    int idx = inputs[b * NFIELD + field];
    const float4* src = (const float4*)(v + (long)idx * FAC);
    union { __hip_bfloat16 h[16]; uint4 u[2]; } tmp;
    float4 a0 = src[0], a1 = src[1], a2 = src[2], a3 = src[3];
    tmp.h[0]  = __float2bfloat16(a0.x); tmp.h[1]  = __float2bfloat16(a0.y);
    tmp.h[2]  = __float2bfloat16(a0.z); tmp.h[3]  = __float2bfloat16(a0.w);
    tmp.h[4]  = __float2bfloat16(a1.x); tmp.h[5]  = __float2bfloat16(a1.y);
    tmp.h[6]  = __float2bfloat16(a1.z); tmp.h[7]  = __float2bfloat16(a1.w);
    tmp.h[8]  = __float2bfloat16(a2.x); tmp.h[9]  = __float2bfloat16(a2.y);
    tmp.h[10] = __float2bfloat16(a2.z); tmp.h[11] = __float2bfloat16(a2.w);
    tmp.h[12] = __float2bfloat16(a3.x); tmp.h[13] = __float2bfloat16(a3.y);
    tmp.h[14] = __float2bfloat16(a3.z); tmp.h[15] = __float2bfloat16(a3.w);
    int bb = b >> 6, row = b & 63;
    __hip_bfloat16* base = xvT + (long)bb * 24576 + field * 1024 + row * 8;
    *(uint4*)base         = tmp.u[0];
    *(uint4*)(base + 512) = tmp.u[1];
}

// Build combo buffer + b2/bias constant. Also zero the pad pair (index PAIRS).
__global__ void prep_w(const float* __restrict__ W1,
                       const float* __restrict__ W2,
                       const float* __restrict__ b1,
                       const float* __restrict__ b2,
                       const float* __restrict__ bsc,
                       char* __restrict__ combo,
                       float* __restrict__ consts) {
    __shared__ float red[256];
    int t = blockIdx.x * 256 + threadIdx.x;      // < 17664
    int p = t >> 6;
    int L = t & 63;
    int q = L >> 4, c = L & 15;
    char* base = combo + (long)p * 4608;
    union { __hip_bfloat16 h[8]; uint4 u; } buf;
#pragma unroll
    for (int tt = 0; tt < 4; ++tt) {
#pragma unroll
        for (int jj = 0; jj < 8; ++jj)
            buf.h[jj] = __float2bfloat16(W1[p * 2048 + (q * 8 + jj) * 64 + tt * 16 + c]);
        *(uint4*)(base + 512 + tt * 1024 + L * 16) = buf.u;
    }
    if (L < 16) {
        float4 bv = {b1[p * 64 + L], b1[p * 64 + 16 + L], b1[p * 64 + 32 + L], b1[p * 64 + 48 + L]};
        *(float4*)(base + L * 16) = bv;
        float4 wv = {W2[p * 64 + L], W2[p * 64 + 16 + L], W2[p * 64 + 32 + L], W2[p * 64 + 48 + L]};
        *(float4*)(base + 256 + L * 16) = wv;
    }
    // zero the pad pair so the tail prefetch reads defined data
    if (blockIdx.x == 1) {
        uint4 z = {0, 0, 0, 0};
        for (int k = threadIdx.x; k < 288; k += 256)
            *(uint4*)(combo + (long)PAIRS * 4608 + k * 16) = z;
    }
    if (blockIdx.x == 0) {
        float s = 0.f;
        for (int k = threadIdx.x; k < PAIRS; k += 256) s += b2[k];
        red[threadIdx.x] = s;
        __syncthreads();
        for (int off = 128; off > 0; off >>= 1) {
            if (threadIdx.x < off) red[threadIdx.x] += red[threadIdx.x + off];
            __syncthreads();
        }
        if (threadIdx.x == 0) consts[0] = red[0] + bsc[0];
    }
}

// Barrier-free main loop: xv slab staged once in LDS (swizzle-padded),
// W1/meta streamed per-wave from L2 with 1-pair register prefetch.
__global__ __launch_bounds__(256, 4) void ffm_main(
        const __hip_bfloat16* __restrict__ xvT,
        const char* __restrict__ combo,
        float* __restrict__ partial) {
    // [field][half][row64][8] with +32 elem (64B) pad per 512-elem half-group
    __shared__ __align__(16) __hip_bfloat16 xv_s[24 * 1088];  // 51 KB

    int tid  = threadIdx.x;
    int bb   = blockIdx.x & (NBB - 1);
    int pg   = blockIdx.x >> 7;          // 0..5
    int lane = tid & 63;
    int wave = tid >> 6;
    int col  = lane & 15;
    int quad = lane >> 4;

    // stage 48KB slab with swizzle: chunk c (16B) -> elem c*8 + (c>>6)*32
    // 3072 chunks total -> 12 iterations of 256 threads
    {
        const uint4* src = (const uint4*)(xvT + (long)bb * 24576);
#pragma unroll
        for (int it = 0; it < 12; ++it) {
            int ch = tid + it * 256;
            *(uint4*)(xv_s + ch * 8 + (ch >> 6) * 32) = src[ch];
        }
    }
    __syncthreads();

    // starting (i,j) for this pair group
    int p0 = pg * PPG;
    int i = 0, rem = p0;
    while (rem >= NFIELD - 1 - i) { rem -= NFIELD - 1 - i; ++i; }
    int j = i + 1 + rem;

    const int arow = (quad & 1) * 544 + (wave * 16 + col) * 8;
    const int mcol = col * 16;
    const char* wp = combo + (long)p0 * 4608;

    // preload pair p0
    float4 mb1 = *(const float4*)(wp + mcol);
    float4 mw2 = *(const float4*)(wp + 256 + mcol);
    bf16x8 f0 = *(const bf16x8*)(wp + 512 + lane * 16);
    bf16x8 f1 = *(const bf16x8*)(wp + 1536 + lane * 16);
    bf16x8 f2 = *(const bf16x8*)(wp + 2560 + lane * 16);
    bf16x8 f3 = *(const bf16x8*)(wp + 3584 + lane * 16);

    float a0 = 0.f, a1 = 0.f, a2 = 0.f, a3 = 0.f;

#pragma unroll 2
    for (int it = 0; it < PPG; ++it) {
        // prefetch next pair (last iter reads the zeroed pad pair; values discarded)
        const char* wn = wp + 4608;
        float4 nb1 = *(const float4*)(wn + mcol);
        float4 nw2 = *(const float4*)(wn + 256 + mcol);
        bf16x8 nf0 = *(const bf16x8*)(wn + 512 + lane * 16);
        bf16x8 nf1 = *(const bf16x8*)(wn + 1536 + lane * 16);
        bf16x8 nf2 = *(const bf16x8*)(wn + 2560 + lane * 16);
        bf16x8 nf3 = *(const bf16x8*)(wn + 3584 + lane * 16);

        int fso = (quad < 2) ? i * 1088 : j * 1088;   // cndmask of two scalars
        bf16x8 af = *(const bf16x8*)(xv_s + fso + arow);

        f32x4 c0 = {mb1.x, mb1.x, mb1.x, mb1.x};
        f32x4 c1 = {mb1.y, mb1.y, mb1.y, mb1.y};
        f32x4 c2 = {mb1.z, mb1.z, mb1.z, mb1.z};
        f32x4 c3 = {mb1.w, mb1.w, mb1.w, mb1.w};
        c0 = __builtin_amdgcn_mfma_f32_16x16x32_bf16(af, f0, c0, 0, 0, 0);
        c1 = __builtin_amdgcn_mfma_f32_16x16x32_bf16(af, f1, c1, 0, 0, 0);
        c2 = __builtin_amdgcn_mfma_f32_16x16x32_bf16(af, f2, c2, 0, 0, 0);
        c3 = __builtin_amdgcn_mfma_f32_16x16x32_bf16(af, f3, c3, 0, 0, 0);

        a0 = fmaf(fmaxf(c0[0], 0.f), mw2.x, a0);
        a1 = fmaf(fmaxf(c0[1], 0.f), mw2.x, a1);
        a2 = fmaf(fmaxf(c0[2], 0.f), mw2.x, a2);
        a3 = fmaf(fmaxf(c0[3], 0.f), mw2.x, a3);
        a0 = fmaf(fmaxf(c1[0], 0.f), mw2.y, a0);
        a1 = fmaf(fmaxf(c1[1], 0.f), mw2.y, a1);
        a2 = fmaf(fmaxf(c1[2], 0.f), mw2.y, a2);
        a3 = fmaf(fmaxf(c1[3], 0.f), mw2.y, a3);
        a0 = fmaf(fmaxf(c2[0], 0.f), mw2.z, a0);
        a1 = fmaf(fmaxf(c2[1], 0.f), mw2.z, a1);
        a2 = fmaf(fmaxf(c2[2], 0.f), mw2.z, a2);
        a3 = fmaf(fmaxf(c2[3], 0.f), mw2.z, a3);
        a0 = fmaf(fmaxf(c3[0], 0.f), mw2.w, a0);
        a1 = fmaf(fmaxf(c3[1], 0.f), mw2.w, a1);
        a2 = fmaf(fmaxf(c3[2], 0.f), mw2.w, a2);
        a3 = fmaf(fmaxf(c3[3], 0.f), mw2.w, a3);

        // rotate prefetch registers
        mb1 = nb1; mw2 = nw2; f0 = nf0; f1 = nf1; f2 = nf2; f3 = nf3;
        wp = wn;
        ++j;
        if (j == NFIELD) { ++i; j = i + 1; }
    }

    // reduce over the 16 column-lanes within each quad group
#pragma unroll
    for (int m = 1; m < 16; m <<= 1) {
        a0 += __shfl_xor(a0, m, 64);
        a1 += __shfl_xor(a1, m, 64);
        a2 += __shfl_xor(a2, m, 64);
        a3 += __shfl_xor(a3, m, 64);
    }
    if (col == 0) {
        f32x4 o; o[0] = a0; o[1] = a1; o[2] = a2; o[3] = a3;
        *(f32x4*)&partial[pg * BATCH + bb * 64 + wave * 16 + quad * 4] = o;
    }
}

__global__ void finalize(const int* __restrict__ inputs,
                         const float* __restrict__ w,
                         const float* __restrict__ consts,
                         const float* __restrict__ partial,
                         float* __restrict__ out) {
    int bidx = blockIdx.x * 256 + threadIdx.x;   // < 8192
    const int4* ip = (const int4*)(inputs + bidx * NFIELD);
    float l = 0.f;
#pragma unroll
    for (int q = 0; q < 6; ++q) {
        int4 v4 = ip[q];
        l += w[v4.x] + w[v4.y] + w[v4.z] + w[v4.w];
    }
    float s = l + consts[0];
#pragma unroll
    for (int g = 0; g < PG; ++g) s += partial[g * BATCH + bidx];
    out[bidx] = 1.0f / (1.0f + expf(-s));
}

extern "C" void kernel_launch(void* const* d_in, const int* in_sizes, int n_in,
                              void* d_out, int out_size, void* d_ws, size_t ws_size,
                              hipStream_t stream) {
    const int*   inputs = (const int*)d_in[0];
    const float* w      = (const float*)d_in[1];
    const float* v      = (const float*)d_in[2];
    const float* bsc    = (const float*)d_in[3];
    const float* W1     = (const float*)d_in[4];
    const float* b1     = (const float*)d_in[5];
    const float* W2     = (const float*)d_in[6];
    const float* b2     = (const float*)d_in[7];
    float* out = (float*)d_out;

    char* ws = (char*)d_ws;
    __hip_bfloat16* xvT = (__hip_bfloat16*)(ws + XVT_OFF);
    char*  combo  = ws + COMBO_OFF;
    float* partial = (float*)(ws + PART_OFF);
    float* consts  = (float*)(ws + CONST_OFF);

    prep_embed<<<BATCH * NFIELD / 256, 256, 0, stream>>>(inputs, v, xvT);
    prep_w<<<PAIRS * 64 / 256, 256, 0, stream>>>(W1, W2, b1, b2, bsc, combo, consts);
    ffm_main<<<NBB * PG, 256, 0, stream>>>(xvT, combo, partial);
    finalize<<<BATCH / 256, 256, 0, stream>>>(inputs, w, consts, partial, out);
}